// Round 2
// baseline (274.292 us; speedup 1.0000x reference)
//
#include <hip/hip_runtime.h>

#define NN 500000
#define RWS 256
#define CLS 1024

__device__ __forceinline__ unsigned f2key(float f){
    unsigned u = __float_as_uint(f);
    return (u & 0x80000000u) ? ~u : (u | 0x80000000u);
}
__device__ __forceinline__ unsigned long long d2key(double d){
    unsigned long long u = (unsigned long long)__double_as_longlong(d);
    return (u & 0x8000000000000000ull) ? ~u : (u | 0x8000000000000000ull);
}
__device__ __forceinline__ double key2d(unsigned long long k){
    unsigned long long u = (k & 0x8000000000000000ull) ? (k & 0x7FFFFFFFFFFFFFFFull) : ~k;
    return __longlong_as_double((long long)u);
}
__device__ __forceinline__ float sigmoidf_(float x){
    return 1.0f / (1.0f + expf(-x));
}

// ---------------- init: zero hist + counters, compute ||scorer|| in f64 ----------------
__global__ void init_kernel(const float* scorer, double* meta_d, unsigned* meta_u, unsigned* hist){
    int t = threadIdx.x;
    for (int i = t; i < 4096; i += 256) hist[i] = 0u;
    __shared__ double red[256];
    double v = (double)scorer[t];
    red[t] = v * v;
    __syncthreads();
    for (int s = 128; s > 0; s >>= 1){
        if (t < s) red[t] += red[t + s];
        __syncthreads();
    }
    if (t == 0){
        meta_d[0] = sqrt(red[0]);   // norm (f64)
        meta_u[2] = 0u;             // thrkey (f32 sortable-key threshold)
        meta_u[3] = 0u;             // candidate count
    }
}

// ---------------- f64 scores + 4096-bin f32-exponent histogram (LDS-privatized) ----------------
__global__ __launch_bounds__(256) void score_kernel(const float4* __restrict__ Z4,
                                                    const float4* __restrict__ scorer4,
                                                    const float* __restrict__ mask,
                                                    const double* __restrict__ meta_d,
                                                    double* __restrict__ scores_d,
                                                    unsigned* __restrict__ hist){
    __shared__ unsigned h[4096];
    int tid = threadIdx.x;
    for (int i = tid; i < 4096; i += 256) h[i] = 0u;
    __syncthreads();
    int lane = tid & 63;
    int w = (blockIdx.x << 2) + (tid >> 6);
    float4 s4 = scorer4[lane];
    double nrm = meta_d[0];
    for (int row = w; row < NN; row += 8192){
        float4 z = Z4[(size_t)row * 64 + lane];
        double d = (double)z.x * s4.x + (double)z.y * s4.y
                 + (double)z.z * s4.z + (double)z.w * s4.w;
        for (int o = 32; o; o >>= 1) d += __shfl_xor(d, o, 64);
        if (lane == 0){
            double sd = d / nrm + (double)mask[row];
            scores_d[row] = sd;
            atomicAdd(&h[f2key((float)sd) >> 20], 1u);
        }
    }
    __syncthreads();
    for (int i = tid; i < 4096; i += 256){
        unsigned c = h[i];
        if (c) atomicAdd(&hist[i], c);
    }
}

// ---------------- find threshold bin (suffix count >= 1024) ----------------
__global__ void scan_kernel(const unsigned* __restrict__ hist, unsigned* meta_u){
    __shared__ unsigned hl[4096];
    __shared__ unsigned part[256];
    int t = threadIdx.x;
    for (int i = t; i < 4096; i += 256) hl[i] = hist[i];
    __syncthreads();
    // thread t covers bins [4096-16(t+1), 4096-16t)  (t=0 = top bins)
    int hi = 4096 - 16 * t;
    unsigned s = 0;
    for (int b = hi - 16; b < hi; ++b) s += hl[b];
    part[t] = s;
    __syncthreads();
    for (int off = 1; off < 256; off <<= 1){
        unsigned v = (t >= off) ? part[t - off] : 0u;
        __syncthreads();
        part[t] += v;
        __syncthreads();
    }
    unsigned incl = part[t];
    unsigned excl = incl - s;
    if (excl < 1024u && incl >= 1024u){
        unsigned c = excl;
        int b;
        for (b = hi - 1; b >= hi - 16; --b){
            c += hl[b];
            if (c >= 1024u) break;
        }
        meta_u[2] = ((unsigned)b) << 20;
    }
}

// ---------------- collect candidates >= threshold bin (store f64 keys) ----------------
__global__ void collect_kernel(const double* __restrict__ scores_d,
                               unsigned* __restrict__ meta_u,
                               unsigned long long* __restrict__ ckey,
                               unsigned* __restrict__ cidx){
    unsigned thr = meta_u[2];
    int i = blockIdx.x * 256 + threadIdx.x;
    if (i < NN){
        double sd = scores_d[i];
        if (f2key((float)sd) >= thr){
            unsigned p = atomicAdd(&meta_u[3], 1u);
            if (p < 4096u){ ckey[p] = d2key(sd); cidx[p] = (unsigned)i; }
        }
    }
}

// ---------------- bitonic sort candidates (f64 key desc, idx asc), emit top 1024 ----------------
__global__ __launch_bounds__(1024) void sort_emit_kernel(const unsigned long long* __restrict__ ckey,
                                                         const unsigned* __restrict__ cidx,
                                                         const unsigned* __restrict__ meta_u,
                                                         unsigned* __restrict__ sel_idx,
                                                         float* __restrict__ sel_t){
    __shared__ unsigned long long sk[4096];
    __shared__ unsigned si[4096];
    int t = threadIdx.x;
    unsigned n = meta_u[3];
    if (n > 4096u) n = 4096u;
    for (int i = t; i < 4096; i += 1024){
        if (i < (int)n){ sk[i] = ckey[i]; si[i] = cidx[i]; }
        else           { sk[i] = 0ull;    si[i] = 0xFFFFFFFFu; }
    }
    __syncthreads();
    for (int k = 2; k <= 4096; k <<= 1){
        for (int j = k >> 1; j > 0; j >>= 1){
            for (int p = t; p < 2048; p += 1024){
                int i = ((p & ~(j - 1)) << 1) | (p & (j - 1));
                int ip = i | j;
                unsigned long long ka = sk[i], kb = sk[ip];
                unsigned ia = si[i], ib = si[ip];
                bool ab = (ka > kb) || (ka == kb && ia < ib);   // a ranks before b
                bool desc = ((i & k) == 0);
                bool sw = desc ? (!ab) : ab;
                if (sw){ sk[i] = kb; sk[ip] = ka; si[i] = ib; si[ip] = ia; }
            }
            __syncthreads();
        }
    }
    sel_idx[t] = si[t];
    sel_t[t] = tanhf((float)key2d(sk[t]));
}

// ---------------- gather+scale: Xc[n][k] = Z[idx_n][k] * tanh_n ----------------
__global__ void gather_kernel(const float4* __restrict__ Z4,
                              const unsigned* __restrict__ sel_idx,
                              const float* __restrict__ sel_t,
                              float4* __restrict__ Xc4){
    int lane = threadIdx.x & 63;
    int col = (blockIdx.x << 2) + (threadIdx.x >> 6);
    unsigned idx = sel_idx[col];
    float tv = sel_t[col];
    float4 z = Z4[(size_t)idx * 64 + lane];
    float4 o; o.x = z.x * tv; o.y = z.y * tv; o.z = z.z * tv; o.w = z.w * tv;
    Xc4[col * 64 + lane] = o;
}

// ---------------- transpose prev_Q -> Qt[n][m] ----------------
__global__ void transposeQ_kernel(const float* __restrict__ Q, float* __restrict__ Qt){
    __shared__ float tile[64][65];
    int n0 = blockIdx.x * 64, m0 = blockIdx.y * 64;
    int t = threadIdx.x;
    for (int rep = 0; rep < 16; ++rep){
        int lin = t + rep * 256;
        int r = lin >> 6, c = lin & 63;
        tile[r][c] = Q[(m0 + r) * 1024 + n0 + c];
    }
    __syncthreads();
    for (int rep = 0; rep < 16; ++rep){
        int lin = t + rep * 256;
        int r = lin >> 6, c = lin & 63;
        Qt[(n0 + r) * 256 + m0 + c] = tile[c][r];
    }
}

// ---------------- GEMM: out[m][n] = sum_k Wsrc[m][k]*Xsrc[n][k] (TN form) ----------------
#define KT 64

__global__ __launch_bounds__(256) void gemm1_kernel(
    const float* __restrict__ Wu, const float* __restrict__ Uu, const float* __restrict__ bu,
    const float* __restrict__ Wr, const float* __restrict__ Ur, const float* __restrict__ br,
    const float* __restrict__ Wh, const float* __restrict__ bh,
    const float* __restrict__ Xc, const float* __restrict__ Qt, const float* __restrict__ Q,
    float* __restrict__ Umat, float* __restrict__ RQt, float* __restrict__ P3)
{
    __shared__ float Ws[64][68];
    __shared__ float Xs[64][68];
    int g  = blockIdx.z;
    int m0 = blockIdx.y * 64, n0 = blockIdx.x * 64;
    int tid = threadIdx.x;
    int tn = tid & 15, tm = tid >> 4;
    float acc[4][4] = {};
    const float* W0 = (g == 0) ? Wu : (g == 1) ? Wr : Wh;
    const float* W1 = (g == 0) ? Uu : (g == 1) ? Ur : Wh; // g==2 never reaches k>=256
    int KMAX = (g == 2) ? 256 : 512;
    for (int k0 = 0; k0 < KMAX; k0 += KT){
        const float* Wsrc = (k0 < 256) ? W0 : W1;
        const float* Xsrc = (k0 < 256) ? Xc : Qt;
        int kl = k0 & 255;
        for (int rep = 0; rep < 4; ++rep){
            int lin = tid + rep * 256;
            int row = lin >> 4;
            int c4 = (lin & 15) << 2;
            float4 wv = *(const float4*)&Wsrc[(m0 + row) * 256 + kl + c4];
            Ws[c4 + 0][row] = wv.x; Ws[c4 + 1][row] = wv.y;
            Ws[c4 + 2][row] = wv.z; Ws[c4 + 3][row] = wv.w;
            float4 xv = *(const float4*)&Xsrc[(n0 + row) * 256 + kl + c4];
            Xs[c4 + 0][row] = xv.x; Xs[c4 + 1][row] = xv.y;
            Xs[c4 + 2][row] = xv.z; Xs[c4 + 3][row] = xv.w;
        }
        __syncthreads();
        #pragma unroll 8
        for (int kk = 0; kk < KT; ++kk){
            float4 a = *(const float4*)&Ws[kk][tm << 2];
            float4 b = *(const float4*)&Xs[kk][tn << 2];
            acc[0][0] += a.x * b.x; acc[0][1] += a.x * b.y; acc[0][2] += a.x * b.z; acc[0][3] += a.x * b.w;
            acc[1][0] += a.y * b.x; acc[1][1] += a.y * b.y; acc[1][2] += a.y * b.z; acc[1][3] += a.y * b.w;
            acc[2][0] += a.z * b.x; acc[2][1] += a.z * b.y; acc[2][2] += a.z * b.z; acc[2][3] += a.z * b.w;
            acc[3][0] += a.w * b.x; acc[3][1] += a.w * b.y; acc[3][2] += a.w * b.z; acc[3][3] += a.w * b.w;
        }
        __syncthreads();
    }
    int mbase = m0 + (tm << 2), nbase = n0 + (tn << 2);
    if (g == 0){
        for (int i = 0; i < 4; ++i){
            float4 bv = *(const float4*)&bu[(mbase + i) * 1024 + nbase];
            float4 o;
            o.x = sigmoidf_(acc[i][0] + bv.x);
            o.y = sigmoidf_(acc[i][1] + bv.y);
            o.z = sigmoidf_(acc[i][2] + bv.z);
            o.w = sigmoidf_(acc[i][3] + bv.w);
            *(float4*)&Umat[(mbase + i) * 1024 + nbase] = o;
        }
    } else if (g == 1){
        float rt[4][4];
        for (int i = 0; i < 4; ++i){
            float4 bv = *(const float4*)&br[(mbase + i) * 1024 + nbase];
            float4 qv = *(const float4*)&Q[(mbase + i) * 1024 + nbase];
            rt[i][0] = sigmoidf_(acc[i][0] + bv.x) * qv.x;
            rt[i][1] = sigmoidf_(acc[i][1] + bv.y) * qv.y;
            rt[i][2] = sigmoidf_(acc[i][2] + bv.z) * qv.z;
            rt[i][3] = sigmoidf_(acc[i][3] + bv.w) * qv.w;
        }
        for (int j = 0; j < 4; ++j){
            float4 o; o.x = rt[0][j]; o.y = rt[1][j]; o.z = rt[2][j]; o.w = rt[3][j];
            *(float4*)&RQt[(nbase + j) * 256 + mbase] = o;
        }
    } else {
        for (int i = 0; i < 4; ++i){
            float4 bv = *(const float4*)&bh[(mbase + i) * 1024 + nbase];
            float4 o;
            o.x = acc[i][0] + bv.x; o.y = acc[i][1] + bv.y;
            o.z = acc[i][2] + bv.z; o.w = acc[i][3] + bv.w;
            *(float4*)&P3[(mbase + i) * 1024 + nbase] = o;
        }
    }
}

__global__ __launch_bounds__(256) void gemm2_kernel(
    const float* __restrict__ Uh, const float* __restrict__ RQt,
    const float* __restrict__ P3, const float* __restrict__ Umat,
    const float* __restrict__ Q, float* __restrict__ out)
{
    __shared__ float Ws[64][68];
    __shared__ float Xs[64][68];
    int m0 = blockIdx.y * 64, n0 = blockIdx.x * 64;
    int tid = threadIdx.x;
    int tn = tid & 15, tm = tid >> 4;
    float acc[4][4] = {};
    for (int k0 = 0; k0 < 256; k0 += KT){
        for (int rep = 0; rep < 4; ++rep){
            int lin = tid + rep * 256;
            int row = lin >> 4;
            int c4 = (lin & 15) << 2;
            float4 wv = *(const float4*)&Uh[(m0 + row) * 256 + k0 + c4];
            Ws[c4 + 0][row] = wv.x; Ws[c4 + 1][row] = wv.y;
            Ws[c4 + 2][row] = wv.z; Ws[c4 + 3][row] = wv.w;
            float4 xv = *(const float4*)&RQt[(n0 + row) * 256 + k0 + c4];
            Xs[c4 + 0][row] = xv.x; Xs[c4 + 1][row] = xv.y;
            Xs[c4 + 2][row] = xv.z; Xs[c4 + 3][row] = xv.w;
        }
        __syncthreads();
        #pragma unroll 8
        for (int kk = 0; kk < KT; ++kk){
            float4 a = *(const float4*)&Ws[kk][tm << 2];
            float4 b = *(const float4*)&Xs[kk][tn << 2];
            acc[0][0] += a.x * b.x; acc[0][1] += a.x * b.y; acc[0][2] += a.x * b.z; acc[0][3] += a.x * b.w;
            acc[1][0] += a.y * b.x; acc[1][1] += a.y * b.y; acc[1][2] += a.y * b.z; acc[1][3] += a.y * b.w;
            acc[2][0] += a.z * b.x; acc[2][1] += a.z * b.y; acc[2][2] += a.z * b.z; acc[2][3] += a.z * b.w;
            acc[3][0] += a.w * b.x; acc[3][1] += a.w * b.y; acc[3][2] += a.w * b.z; acc[3][3] += a.w * b.w;
        }
        __syncthreads();
    }
    int mbase = m0 + (tm << 2), nbase = n0 + (tn << 2);
    for (int i = 0; i < 4; ++i){
        float4 p = *(const float4*)&P3[(mbase + i) * 1024 + nbase];
        float4 u = *(const float4*)&Umat[(mbase + i) * 1024 + nbase];
        float4 q = *(const float4*)&Q[(mbase + i) * 1024 + nbase];
        float4 o;
        float h0 = fmaxf(acc[i][0] + p.x, 0.0f);
        float h1 = fmaxf(acc[i][1] + p.y, 0.0f);
        float h2 = fmaxf(acc[i][2] + p.z, 0.0f);
        float h3 = fmaxf(acc[i][3] + p.w, 0.0f);
        o.x = (1.0f - u.x) * q.x + u.x * h0;
        o.y = (1.0f - u.y) * q.y + u.y * h1;
        o.z = (1.0f - u.z) * q.z + u.z * h2;
        o.w = (1.0f - u.w) * q.w + u.w * h3;
        *(float4*)&out[(mbase + i) * 1024 + nbase] = o;
    }
}

extern "C" void kernel_launch(void* const* d_in, const int* in_sizes, int n_in,
                              void* d_out, int out_size, void* d_ws, size_t ws_size,
                              hipStream_t stream)
{
    const float* prev_Q = (const float*)d_in[0];
    const float* prev_Z = (const float*)d_in[1];
    const float* mask   = (const float*)d_in[2];
    const float* scorer = (const float*)d_in[3];
    const float* W_u = (const float*)d_in[4];
    const float* U_u = (const float*)d_in[5];
    const float* b_u = (const float*)d_in[6];
    const float* W_r = (const float*)d_in[7];
    const float* U_r = (const float*)d_in[8];
    const float* b_r = (const float*)d_in[9];
    const float* W_h = (const float*)d_in[10];
    const float* U_h = (const float*)d_in[11];
    const float* b_h = (const float*)d_in[12];

    char* ws = (char*)d_ws;
    double*             scores_d = (double*)            (ws + 0);
    unsigned*           hist     = (unsigned*)          (ws + 4000256);
    double*             meta_d   = (double*)            (ws + 4016640);
    unsigned*           meta_u   = (unsigned*)          (ws + 4016640);
    unsigned long long* ckey     = (unsigned long long*)(ws + 4016704);
    unsigned*           cidx     = (unsigned*)          (ws + 4049472);
    unsigned*           sel_idx  = (unsigned*)          (ws + 4065856);
    float*              sel_t    = (float*)             (ws + 4069952);
    float*              Xc       = (float*)             (ws + 4074496);
    float*              Qt       = (float*)             (ws + 5123072);
    float*              Umat     = (float*)             (ws + 6171648);
    float*              RQt      = (float*)             (ws + 7220224);
    float*              P3       = (float*)             (ws + 8268800);

    hipLaunchKernelGGL(init_kernel, dim3(1), dim3(256), 0, stream,
                       scorer, meta_d, meta_u, hist);
    hipLaunchKernelGGL(score_kernel, dim3(2048), dim3(256), 0, stream,
                       (const float4*)prev_Z, (const float4*)scorer, mask, meta_d, scores_d, hist);
    hipLaunchKernelGGL(scan_kernel, dim3(1), dim3(256), 0, stream, hist, meta_u);
    hipLaunchKernelGGL(collect_kernel, dim3(1954), dim3(256), 0, stream,
                       scores_d, meta_u, ckey, cidx);
    hipLaunchKernelGGL(sort_emit_kernel, dim3(1), dim3(1024), 0, stream,
                       ckey, cidx, meta_u, sel_idx, sel_t);
    hipLaunchKernelGGL(gather_kernel, dim3(256), dim3(256), 0, stream,
                       (const float4*)prev_Z, sel_idx, sel_t, (float4*)Xc);
    hipLaunchKernelGGL(transposeQ_kernel, dim3(16, 4), dim3(256), 0, stream, prev_Q, Qt);
    hipLaunchKernelGGL(gemm1_kernel, dim3(16, 4, 3), dim3(256), 0, stream,
                       W_u, U_u, b_u, W_r, U_r, b_r, W_h, b_h, Xc, Qt, prev_Q,
                       Umat, RQt, P3);
    hipLaunchKernelGGL(gemm2_kernel, dim3(16, 4), dim3(256), 0, stream,
                       U_h, RQt, P3, Umat, prev_Q, (float*)d_out);
}

// Round 3
// 240.201 us; speedup vs baseline: 1.1419x; 1.1419x over previous
//
#include <hip/hip_runtime.h>

#define NN 500000

__device__ __forceinline__ unsigned f2key(float f){
    unsigned u = __float_as_uint(f);
    return (u & 0x80000000u) ? ~u : (u | 0x80000000u);
}
__device__ __forceinline__ unsigned long long d2key(double d){
    unsigned long long u = (unsigned long long)__double_as_longlong(d);
    return (u & 0x8000000000000000ull) ? ~u : (u | 0x8000000000000000ull);
}
__device__ __forceinline__ double key2d(unsigned long long k){
    unsigned long long u = (k & 0x8000000000000000ull) ? (k & 0x7FFFFFFFFFFFFFFFull) : ~k;
    return __longlong_as_double((long long)u);
}
__device__ __forceinline__ float sigmoidf_(float x){
    return 1.0f / (1.0f + expf(-x));
}

// ---- scores (f64, 16-lane row groups) + 4096-bin histogram; norm computed in-block ----
__global__ __launch_bounds__(256) void score_kernel(const float4* __restrict__ Z4,
                                                    const float4* __restrict__ scorer4,
                                                    const float* __restrict__ mask,
                                                    double* __restrict__ scores_d,
                                                    unsigned* __restrict__ hist){
    __shared__ unsigned h[4096];
    __shared__ double nred[256];
    __shared__ double s_invn;
    int tid = threadIdx.x;
    for (int i = tid; i < 4096; i += 256) h[i] = 0u;
    // block-local ||scorer|| (deterministic tree reduce, identical in every block)
    {
        const float* sc = (const float*)scorer4;
        double v = (double)sc[tid];
        nred[tid] = v * v;
        __syncthreads();
        for (int s = 128; s > 0; s >>= 1){
            if (tid < s) nred[tid] += nred[tid + s];
            __syncthreads();
        }
        if (tid == 0) s_invn = 1.0 / sqrt(nred[0]);
        __syncthreads();
    }
    double invn = s_invn;
    int sl = tid & 15;            // lane within 16-lane row group
    int sub = (tid >> 4) & 3;     // row group within wave
    int wid = blockIdx.x * 4 + (tid >> 6);
    // preload scorer fragment: cols sl*16 .. sl*16+15
    float4 s0 = scorer4[sl * 4 + 0];
    float4 s1 = scorer4[sl * 4 + 1];
    float4 s2 = scorer4[sl * 4 + 2];
    float4 s3 = scorer4[sl * 4 + 3];
    for (int r = wid * 4 + sub; r < NN; r += 32768){
        const float4* zp = Z4 + (size_t)r * 64 + sl * 4;
        float4 z0 = zp[0], z1 = zp[1], z2 = zp[2], z3 = zp[3];
        double d = (double)z0.x * s0.x + (double)z0.y * s0.y + (double)z0.z * s0.z + (double)z0.w * s0.w
                 + (double)z1.x * s1.x + (double)z1.y * s1.y + (double)z1.z * s1.z + (double)z1.w * s1.w
                 + (double)z2.x * s2.x + (double)z2.y * s2.y + (double)z2.z * s2.z + (double)z2.w * s2.w
                 + (double)z3.x * s3.x + (double)z3.y * s3.y + (double)z3.z * s3.z + (double)z3.w * s3.w;
        d += __shfl_xor(d, 8, 16);
        d += __shfl_xor(d, 4, 16);
        d += __shfl_xor(d, 2, 16);
        d += __shfl_xor(d, 1, 16);
        if (sl == 0){
            double sd = d * invn + (double)mask[r];
            scores_d[r] = sd;
            atomicAdd(&h[f2key((float)sd) >> 20], 1u);
        }
    }
    __syncthreads();
    for (int i = tid; i < 4096; i += 256){
        unsigned c = h[i];
        if (c) atomicAdd(&hist[i], c);
    }
}

// ---------------- find threshold bin (suffix count >= 1024) ----------------
__global__ void scan_kernel(const unsigned* __restrict__ hist, unsigned* meta_u){
    __shared__ unsigned hl[4096];
    __shared__ unsigned part[256];
    int t = threadIdx.x;
    for (int i = t; i < 4096; i += 256) hl[i] = hist[i];
    __syncthreads();
    int hi = 4096 - 16 * t;
    unsigned s = 0;
    for (int b = hi - 16; b < hi; ++b) s += hl[b];
    part[t] = s;
    __syncthreads();
    for (int off = 1; off < 256; off <<= 1){
        unsigned v = (t >= off) ? part[t - off] : 0u;
        __syncthreads();
        part[t] += v;
        __syncthreads();
    }
    unsigned incl = part[t];
    unsigned excl = incl - s;
    if (excl < 1024u && incl >= 1024u){
        unsigned c = excl;
        int b;
        for (b = hi - 1; b >= hi - 16; --b){
            c += hl[b];
            if (c >= 1024u) break;
        }
        meta_u[2] = ((unsigned)b) << 20;
    }
}

// ---------------- collect candidates >= threshold bin (f64 keys) ----------------
__global__ void collect_kernel(const double* __restrict__ scores_d,
                               unsigned* __restrict__ meta_u,
                               unsigned long long* __restrict__ ckey,
                               unsigned* __restrict__ cidx){
    unsigned thr = meta_u[2];
    int i = blockIdx.x * 256 + threadIdx.x;
    if (i < NN){
        double sd = scores_d[i];
        if (f2key((float)sd) >= thr){
            unsigned p = atomicAdd(&meta_u[3], 1u);
            if (p < 4096u){ ckey[p] = d2key(sd); cidx[p] = (unsigned)i; }
        }
    }
}

// ------- bitonic sort m=next_pow2(n) candidates (key desc, idx asc), emit top 1024 -------
__global__ __launch_bounds__(1024) void sort_emit_kernel(const unsigned long long* __restrict__ ckey,
                                                         const unsigned* __restrict__ cidx,
                                                         const unsigned* __restrict__ meta_u,
                                                         unsigned* __restrict__ sel_idx,
                                                         float* __restrict__ sel_t){
    __shared__ unsigned long long sk[4096];
    __shared__ unsigned si[4096];
    int t = threadIdx.x;
    unsigned n = meta_u[3];
    if (n > 4096u) n = 4096u;
    int m = 1024;
    while (m < (int)n) m <<= 1;
    for (int i = t; i < m; i += 1024){
        if (i < (int)n){ sk[i] = ckey[i]; si[i] = cidx[i]; }
        else           { sk[i] = 0ull;    si[i] = 0xFFFFFFFFu; }
    }
    __syncthreads();
    int m2 = m >> 1;
    for (int k = 2; k <= m; k <<= 1){
        for (int j = k >> 1; j > 0; j >>= 1){
            for (int p = t; p < m2; p += 1024){
                int i = ((p & ~(j - 1)) << 1) | (p & (j - 1));
                int ip = i | j;
                unsigned long long ka = sk[i], kb = sk[ip];
                unsigned ia = si[i], ib = si[ip];
                bool ab = (ka > kb) || (ka == kb && ia < ib);
                bool desc = ((i & k) == 0);
                bool sw = desc ? (!ab) : ab;
                if (sw){ sk[i] = kb; sk[ip] = ka; si[i] = ib; si[ip] = ia; }
            }
            __syncthreads();
        }
    }
    sel_idx[t] = si[t];
    sel_t[t] = tanhf((float)key2d(sk[t]));
}

// ---------------- gather+scale: Xc[n][k] = Z[idx_n][k] * tanh_n ----------------
__global__ void gather_kernel(const float4* __restrict__ Z4,
                              const unsigned* __restrict__ sel_idx,
                              const float* __restrict__ sel_t,
                              float4* __restrict__ Xc4){
    int lane = threadIdx.x & 63;
    int col = (blockIdx.x << 2) + (threadIdx.x >> 6);
    unsigned idx = sel_idx[col];
    float tv = sel_t[col];
    float4 z = Z4[(size_t)idx * 64 + lane];
    float4 o; o.x = z.x * tv; o.y = z.y * tv; o.z = z.z * tv; o.w = z.w * tv;
    Xc4[col * 64 + lane] = o;
}

// ---- GEMM1: out[m][n] = W@z_topk (k<256, from Xc[n][k]) + U@Q (k>=256, direct from Q[k][n]) ----
#define KT 64

__global__ __launch_bounds__(256) void gemm1_kernel(
    const float* __restrict__ Wu, const float* __restrict__ Uu, const float* __restrict__ bu,
    const float* __restrict__ Wr, const float* __restrict__ Ur, const float* __restrict__ br,
    const float* __restrict__ Wh, const float* __restrict__ bh,
    const float* __restrict__ Xc, const float* __restrict__ Q,
    float* __restrict__ Umat, float* __restrict__ RQm, float* __restrict__ P3)
{
    __shared__ float Ws[64][68];
    __shared__ float Xs[64][68];
    int g  = blockIdx.z;
    int m0 = blockIdx.y * 64, n0 = blockIdx.x * 64;
    int tid = threadIdx.x;
    int tn = tid & 15, tm = tid >> 4;
    float acc[4][4] = {};
    const float* W0 = (g == 0) ? Wu : (g == 1) ? Wr : Wh;
    const float* W1 = (g == 0) ? Uu : (g == 1) ? Ur : Wh; // g==2 never reaches k>=256
    int KMAX = (g == 2) ? 256 : 512;
    for (int k0 = 0; k0 < KMAX; k0 += KT){
        const float* Wsrc = (k0 < 256) ? W0 : W1;
        int kl = k0 & 255;
        for (int rep = 0; rep < 4; ++rep){
            int lin = tid + rep * 256;
            int row = lin >> 4;
            int c4 = (lin & 15) << 2;
            float4 wv = *(const float4*)&Wsrc[(m0 + row) * 256 + kl + c4];
            Ws[c4 + 0][row] = wv.x; Ws[c4 + 1][row] = wv.y;
            Ws[c4 + 2][row] = wv.z; Ws[c4 + 3][row] = wv.w;
        }
        if (k0 < 256){
            for (int rep = 0; rep < 4; ++rep){
                int lin = tid + rep * 256;
                int row = lin >> 4;          // n within tile
                int c4 = (lin & 15) << 2;    // k within tile
                float4 xv = *(const float4*)&Xc[(n0 + row) * 256 + kl + c4];
                Xs[c4 + 0][row] = xv.x; Xs[c4 + 1][row] = xv.y;
                Xs[c4 + 2][row] = xv.z; Xs[c4 + 3][row] = xv.w;
            }
        } else {
            int kq = k0 - 256;
            for (int rep = 0; rep < 4; ++rep){
                int lin = tid + rep * 256;
                int row = lin >> 4;          // k within tile
                int c4 = (lin & 15) << 2;    // n within tile
                float4 qv = *(const float4*)&Q[(kq + row) * 1024 + n0 + c4];
                *(float4*)&Xs[row][c4] = qv;
            }
        }
        __syncthreads();
        #pragma unroll 8
        for (int kk = 0; kk < KT; ++kk){
            float4 a = *(const float4*)&Ws[kk][tm << 2];
            float4 b = *(const float4*)&Xs[kk][tn << 2];
            acc[0][0] += a.x * b.x; acc[0][1] += a.x * b.y; acc[0][2] += a.x * b.z; acc[0][3] += a.x * b.w;
            acc[1][0] += a.y * b.x; acc[1][1] += a.y * b.y; acc[1][2] += a.y * b.z; acc[1][3] += a.y * b.w;
            acc[2][0] += a.z * b.x; acc[2][1] += a.z * b.y; acc[2][2] += a.z * b.z; acc[2][3] += a.z * b.w;
            acc[3][0] += a.w * b.x; acc[3][1] += a.w * b.y; acc[3][2] += a.w * b.z; acc[3][3] += a.w * b.w;
        }
        __syncthreads();
    }
    int mbase = m0 + (tm << 2), nbase = n0 + (tn << 2);
    if (g == 0){
        for (int i = 0; i < 4; ++i){
            float4 bv = *(const float4*)&bu[(mbase + i) * 1024 + nbase];
            float4 o;
            o.x = sigmoidf_(acc[i][0] + bv.x);
            o.y = sigmoidf_(acc[i][1] + bv.y);
            o.z = sigmoidf_(acc[i][2] + bv.z);
            o.w = sigmoidf_(acc[i][3] + bv.w);
            *(float4*)&Umat[(mbase + i) * 1024 + nbase] = o;
        }
    } else if (g == 1){
        for (int i = 0; i < 4; ++i){
            float4 bv = *(const float4*)&br[(mbase + i) * 1024 + nbase];
            float4 qv = *(const float4*)&Q[(mbase + i) * 1024 + nbase];
            float4 o;
            o.x = sigmoidf_(acc[i][0] + bv.x) * qv.x;
            o.y = sigmoidf_(acc[i][1] + bv.y) * qv.y;
            o.z = sigmoidf_(acc[i][2] + bv.z) * qv.z;
            o.w = sigmoidf_(acc[i][3] + bv.w) * qv.w;
            *(float4*)&RQm[(mbase + i) * 1024 + nbase] = o;
        }
    } else {
        for (int i = 0; i < 4; ++i){
            float4 bv = *(const float4*)&bh[(mbase + i) * 1024 + nbase];
            float4 o;
            o.x = acc[i][0] + bv.x; o.y = acc[i][1] + bv.y;
            o.z = acc[i][2] + bv.z; o.w = acc[i][3] + bv.w;
            *(float4*)&P3[(mbase + i) * 1024 + nbase] = o;
        }
    }
}

// ---- GEMM2: out = (1-u)*Q + u*relu(U_h@(r*Q) + P3); X staged direct from RQm[k][n] ----
__global__ __launch_bounds__(256) void gemm2_kernel(
    const float* __restrict__ Uh, const float* __restrict__ RQm,
    const float* __restrict__ P3, const float* __restrict__ Umat,
    const float* __restrict__ Q, float* __restrict__ out)
{
    __shared__ float Ws[64][68];
    __shared__ float Xs[64][68];
    int m0 = blockIdx.y * 64, n0 = blockIdx.x * 64;
    int tid = threadIdx.x;
    int tn = tid & 15, tm = tid >> 4;
    float acc[4][4] = {};
    for (int k0 = 0; k0 < 256; k0 += KT){
        for (int rep = 0; rep < 4; ++rep){
            int lin = tid + rep * 256;
            int row = lin >> 4;
            int c4 = (lin & 15) << 2;
            float4 wv = *(const float4*)&Uh[(m0 + row) * 256 + k0 + c4];
            Ws[c4 + 0][row] = wv.x; Ws[c4 + 1][row] = wv.y;
            Ws[c4 + 2][row] = wv.z; Ws[c4 + 3][row] = wv.w;
        }
        for (int rep = 0; rep < 4; ++rep){
            int lin = tid + rep * 256;
            int row = lin >> 4;          // k within tile
            int c4 = (lin & 15) << 2;    // n within tile
            float4 xv = *(const float4*)&RQm[(k0 + row) * 1024 + n0 + c4];
            *(float4*)&Xs[row][c4] = xv;
        }
        __syncthreads();
        #pragma unroll 8
        for (int kk = 0; kk < KT; ++kk){
            float4 a = *(const float4*)&Ws[kk][tm << 2];
            float4 b = *(const float4*)&Xs[kk][tn << 2];
            acc[0][0] += a.x * b.x; acc[0][1] += a.x * b.y; acc[0][2] += a.x * b.z; acc[0][3] += a.x * b.w;
            acc[1][0] += a.y * b.x; acc[1][1] += a.y * b.y; acc[1][2] += a.y * b.z; acc[1][3] += a.y * b.w;
            acc[2][0] += a.z * b.x; acc[2][1] += a.z * b.y; acc[2][2] += a.z * b.z; acc[2][3] += a.z * b.w;
            acc[3][0] += a.w * b.x; acc[3][1] += a.w * b.y; acc[3][2] += a.w * b.z; acc[3][3] += a.w * b.w;
        }
        __syncthreads();
    }
    int mbase = m0 + (tm << 2), nbase = n0 + (tn << 2);
    for (int i = 0; i < 4; ++i){
        float4 p = *(const float4*)&P3[(mbase + i) * 1024 + nbase];
        float4 u = *(const float4*)&Umat[(mbase + i) * 1024 + nbase];
        float4 q = *(const float4*)&Q[(mbase + i) * 1024 + nbase];
        float4 o;
        float h0 = fmaxf(acc[i][0] + p.x, 0.0f);
        float h1 = fmaxf(acc[i][1] + p.y, 0.0f);
        float h2 = fmaxf(acc[i][2] + p.z, 0.0f);
        float h3 = fmaxf(acc[i][3] + p.w, 0.0f);
        o.x = (1.0f - u.x) * q.x + u.x * h0;
        o.y = (1.0f - u.y) * q.y + u.y * h1;
        o.z = (1.0f - u.z) * q.z + u.z * h2;
        o.w = (1.0f - u.w) * q.w + u.w * h3;
        *(float4*)&out[(mbase + i) * 1024 + nbase] = o;
    }
}

extern "C" void kernel_launch(void* const* d_in, const int* in_sizes, int n_in,
                              void* d_out, int out_size, void* d_ws, size_t ws_size,
                              hipStream_t stream)
{
    const float* prev_Q = (const float*)d_in[0];
    const float* prev_Z = (const float*)d_in[1];
    const float* mask   = (const float*)d_in[2];
    const float* scorer = (const float*)d_in[3];
    const float* W_u = (const float*)d_in[4];
    const float* U_u = (const float*)d_in[5];
    const float* b_u = (const float*)d_in[6];
    const float* W_r = (const float*)d_in[7];
    const float* U_r = (const float*)d_in[8];
    const float* b_r = (const float*)d_in[9];
    const float* W_h = (const float*)d_in[10];
    const float* U_h = (const float*)d_in[11];
    const float* b_h = (const float*)d_in[12];

    char* ws = (char*)d_ws;
    double*             scores_d = (double*)            (ws + 0);
    unsigned*           hist     = (unsigned*)          (ws + 4000256);
    unsigned*           meta_u   = (unsigned*)          (ws + 4016640);
    unsigned long long* ckey     = (unsigned long long*)(ws + 4016704);
    unsigned*           cidx     = (unsigned*)          (ws + 4049472);
    unsigned*           sel_idx  = (unsigned*)          (ws + 4065856);
    float*              sel_t    = (float*)             (ws + 4069952);
    float*              Xc       = (float*)             (ws + 4100096);
    float*              RQm      = (float*)             (ws + 5148672);
    float*              Umat     = (float*)             (ws + 6197248);
    float*              P3       = (float*)             (ws + 7245824);

    // zero hist + meta (16384 + 64 bytes)
    hipMemsetAsync(ws + 4000256, 0, 16448, stream);
    hipLaunchKernelGGL(score_kernel, dim3(2048), dim3(256), 0, stream,
                       (const float4*)prev_Z, (const float4*)scorer, mask, scores_d, hist);
    hipLaunchKernelGGL(scan_kernel, dim3(1), dim3(256), 0, stream, hist, meta_u);
    hipLaunchKernelGGL(collect_kernel, dim3(1954), dim3(256), 0, stream,
                       scores_d, meta_u, ckey, cidx);
    hipLaunchKernelGGL(sort_emit_kernel, dim3(1), dim3(1024), 0, stream,
                       ckey, cidx, meta_u, sel_idx, sel_t);
    hipLaunchKernelGGL(gather_kernel, dim3(256), dim3(256), 0, stream,
                       (const float4*)prev_Z, sel_idx, sel_t, (float4*)Xc);
    hipLaunchKernelGGL(gemm1_kernel, dim3(16, 4, 3), dim3(256), 0, stream,
                       W_u, U_u, b_u, W_r, U_r, b_r, W_h, b_h, Xc, prev_Q,
                       Umat, RQm, P3);
    hipLaunchKernelGGL(gemm2_kernel, dim3(16, 4), dim3(256), 0, stream,
                       U_h, RQm, P3, Umat, prev_Q, (float*)d_out);
}

// Round 4
// 201.982 us; speedup vs baseline: 1.3580x; 1.1892x over previous
//
#include <hip/hip_runtime.h>
#include <hip/hip_bf16.h>

#define NN 500000

typedef short bf16x8 __attribute__((ext_vector_type(8)));
typedef float f32x4 __attribute__((ext_vector_type(4)));

__device__ __forceinline__ unsigned f2key(float f){
    unsigned u = __float_as_uint(f);
    return (u & 0x80000000u) ? ~u : (u | 0x80000000u);
}
__device__ __forceinline__ unsigned long long d2key(double d){
    unsigned long long u = (unsigned long long)__double_as_longlong(d);
    return (u & 0x8000000000000000ull) ? ~u : (u | 0x8000000000000000ull);
}
__device__ __forceinline__ double key2d(unsigned long long k){
    unsigned long long u = (k & 0x8000000000000000ull) ? (k & 0x7FFFFFFFFFFFFFFFull) : ~k;
    return __longlong_as_double((long long)u);
}
__device__ __forceinline__ float sigmoidf_(float x){
    return 1.0f / (1.0f + expf(-x));
}
__device__ __forceinline__ short f2bf(float x){
    __hip_bfloat16 h = __float2bfloat16(x);
    return *reinterpret_cast<short*>(&h);
}

// ---- scores (f64, 16-lane row groups, interleaved-coalesced) + 4096-bin histogram ----
__global__ __launch_bounds__(256) void score_kernel(const float4* __restrict__ Z4,
                                                    const float4* __restrict__ scorer4,
                                                    const float* __restrict__ mask,
                                                    double* __restrict__ scores_d,
                                                    unsigned* __restrict__ hist){
    __shared__ unsigned h[4096];
    __shared__ double nred[256];
    __shared__ double s_invn;
    int tid = threadIdx.x;
    for (int i = tid; i < 4096; i += 256) h[i] = 0u;
    {
        const float* sc = (const float*)scorer4;
        double v = (double)sc[tid];
        nred[tid] = v * v;
        __syncthreads();
        for (int s = 128; s > 0; s >>= 1){
            if (tid < s) nred[tid] += nred[tid + s];
            __syncthreads();
        }
        if (tid == 0) s_invn = 1.0 / sqrt(nred[0]);
        __syncthreads();
    }
    double invn = s_invn;
    int sl = tid & 15;
    int sub = (tid >> 4) & 3;
    int wid = blockIdx.x * 4 + (tid >> 6);
    // interleaved columns: lane sl owns float4s {sl, sl+16, sl+32, sl+48}
    float4 s0 = scorer4[sl], s1 = scorer4[sl + 16], s2 = scorer4[sl + 32], s3 = scorer4[sl + 48];
    for (int r = wid * 4 + sub; r < NN; r += 16384){
        const float4* zp = Z4 + (size_t)r * 64;
        float4 z0 = zp[sl], z1 = zp[sl + 16], z2 = zp[sl + 32], z3 = zp[sl + 48];
        double d = (double)z0.x * s0.x + (double)z0.y * s0.y + (double)z0.z * s0.z + (double)z0.w * s0.w
                 + (double)z1.x * s1.x + (double)z1.y * s1.y + (double)z1.z * s1.z + (double)z1.w * s1.w
                 + (double)z2.x * s2.x + (double)z2.y * s2.y + (double)z2.z * s2.z + (double)z2.w * s2.w
                 + (double)z3.x * s3.x + (double)z3.y * s3.y + (double)z3.z * s3.z + (double)z3.w * s3.w;
        d += __shfl_xor(d, 8, 16);
        d += __shfl_xor(d, 4, 16);
        d += __shfl_xor(d, 2, 16);
        d += __shfl_xor(d, 1, 16);
        if (sl == 0){
            double sd = d * invn + (double)mask[r];
            scores_d[r] = sd;
            atomicAdd(&h[f2key((float)sd) >> 20], 1u);
        }
    }
    __syncthreads();
    for (int i = tid; i < 4096; i += 256){
        unsigned c = h[i];
        if (c) atomicAdd(&hist[i], c);
    }
}

// ---------------- find threshold bin (suffix count >= 1024) ----------------
__global__ void scan_kernel(const unsigned* __restrict__ hist, unsigned* meta_u){
    __shared__ unsigned hl[4096];
    __shared__ unsigned part[256];
    int t = threadIdx.x;
    for (int i = t; i < 4096; i += 256) hl[i] = hist[i];
    __syncthreads();
    int hi = 4096 - 16 * t;
    unsigned s = 0;
    for (int b = hi - 16; b < hi; ++b) s += hl[b];
    part[t] = s;
    __syncthreads();
    for (int off = 1; off < 256; off <<= 1){
        unsigned v = (t >= off) ? part[t - off] : 0u;
        __syncthreads();
        part[t] += v;
        __syncthreads();
    }
    unsigned incl = part[t];
    unsigned excl = incl - s;
    if (excl < 1024u && incl >= 1024u){
        unsigned c = excl;
        int b;
        for (b = hi - 1; b >= hi - 16; --b){
            c += hl[b];
            if (c >= 1024u) break;
        }
        meta_u[2] = ((unsigned)b) << 20;
    }
}

// ---------------- collect candidates >= threshold bin (f64 keys) ----------------
__global__ void collect_kernel(const double* __restrict__ scores_d,
                               unsigned* __restrict__ meta_u,
                               unsigned long long* __restrict__ ckey,
                               unsigned* __restrict__ cidx){
    unsigned thr = meta_u[2];
    int i = blockIdx.x * 256 + threadIdx.x;
    if (i < NN){
        double sd = scores_d[i];
        if (f2key((float)sd) >= thr){
            unsigned p = atomicAdd(&meta_u[3], 1u);
            if (p < 4096u){ ckey[p] = d2key(sd); cidx[p] = (unsigned)i; }
        }
    }
}

// ------- bitonic sort m=next_pow2(n) candidates (key desc, idx asc), emit top 1024 -------
__global__ __launch_bounds__(1024) void sort_emit_kernel(const unsigned long long* __restrict__ ckey,
                                                         const unsigned* __restrict__ cidx,
                                                         const unsigned* __restrict__ meta_u,
                                                         unsigned* __restrict__ sel_idx,
                                                         float* __restrict__ sel_t){
    __shared__ unsigned long long sk[4096];
    __shared__ unsigned si[4096];
    int t = threadIdx.x;
    unsigned n = meta_u[3];
    if (n > 4096u) n = 4096u;
    int m = 1024;
    while (m < (int)n) m <<= 1;
    for (int i = t; i < m; i += 1024){
        if (i < (int)n){ sk[i] = ckey[i]; si[i] = cidx[i]; }
        else           { sk[i] = 0ull;    si[i] = 0xFFFFFFFFu; }
    }
    __syncthreads();
    int m2 = m >> 1;
    for (int k = 2; k <= m; k <<= 1){
        for (int j = k >> 1; j > 0; j >>= 1){
            for (int p = t; p < m2; p += 1024){
                int i = ((p & ~(j - 1)) << 1) | (p & (j - 1));
                int ip = i | j;
                unsigned long long ka = sk[i], kb = sk[ip];
                unsigned ia = si[i], ib = si[ip];
                bool ab = (ka > kb) || (ka == kb && ia < ib);
                bool desc = ((i & k) == 0);
                bool sw = desc ? (!ab) : ab;
                if (sw){ sk[i] = kb; sk[ip] = ka; si[i] = ib; si[ip] = ia; }
            }
            __syncthreads();
        }
    }
    sel_idx[t] = si[t];
    sel_t[t] = tanhf((float)key2d(sk[t]));
}

// ---------------- gather+scale: Xc[n][k] = Z[idx_n][k] * tanh_n ----------------
__global__ void gather_kernel(const float4* __restrict__ Z4,
                              const unsigned* __restrict__ sel_idx,
                              const float* __restrict__ sel_t,
                              float4* __restrict__ Xc4){
    int lane = threadIdx.x & 63;
    int col = (blockIdx.x << 2) + (threadIdx.x >> 6);
    unsigned idx = sel_idx[col];
    float tv = sel_t[col];
    float4 z = Z4[(size_t)idx * 64 + lane];
    float4 o; o.x = z.x * tv; o.y = z.y * tv; o.z = z.z * tv; o.w = z.w * tv;
    Xc4[col * 64 + lane] = o;
}

// ---------------- transpose prev_Q -> Qt[n][m] ----------------
__global__ void transposeQ_kernel(const float* __restrict__ Q, float* __restrict__ Qt){
    __shared__ float tile[64][65];
    int n0 = blockIdx.x * 64, m0 = blockIdx.y * 64;
    int t = threadIdx.x;
    for (int rep = 0; rep < 16; ++rep){
        int lin = t + rep * 256;
        int r = lin >> 6, c = lin & 63;
        tile[r][c] = Q[(m0 + r) * 1024 + n0 + c];
    }
    __syncthreads();
    for (int rep = 0; rep < 16; ++rep){
        int lin = t + rep * 256;
        int r = lin >> 6, c = lin & 63;
        Qt[(n0 + r) * 256 + m0 + c] = tile[c][r];
    }
}

// ===================== bf16 MFMA GEMMs =====================
// Block: 256 threads = 4 waves. Tile 64m x 64n. Wave w owns rows [w*16,(w+1)*16), all 64 n.
// LDS: As[row m][64 k] bf16, Xs[row n][64 k] bf16, XOR-swizzled: kbyte ^= (row&7)<<4.
// MFMA 16x16x32: A row=lane&15, k=(lane>>4)*8+j ; B col=lane&15, same k ;
//                D col=lane&15, row=(lane>>4)*4+reg.

__global__ __launch_bounds__(256) void gemm1_mfma(
    const float* __restrict__ Wu, const float* __restrict__ Uu, const float* __restrict__ bu,
    const float* __restrict__ Wr, const float* __restrict__ Ur, const float* __restrict__ br,
    const float* __restrict__ Wh, const float* __restrict__ bh,
    const float* __restrict__ Xc, const float* __restrict__ Qt, const float* __restrict__ Q,
    float* __restrict__ Umat, float* __restrict__ RQt, float* __restrict__ P3)
{
    __shared__ short As[4096];
    __shared__ short Xs[4096];
    int g = blockIdx.z;
    int n0 = blockIdx.x * 64, m0 = blockIdx.y * 64;
    int tid = threadIdx.x;
    int l = tid & 63, w = tid >> 6;
    int q = l >> 4, c16 = l & 15;
    f32x4 acc[4];
    #pragma unroll
    for (int i = 0; i < 4; ++i) acc[i] = (f32x4){0.f, 0.f, 0.f, 0.f};
    const float* W0 = (g == 0) ? Wu : (g == 1) ? Wr : Wh;
    const float* W1 = (g == 0) ? Uu : (g == 1) ? Ur : Wh;
    int KMAX = (g == 2) ? 256 : 512;
    for (int k0 = 0; k0 < KMAX; k0 += 64){
        const float* Asrc = (k0 < 256) ? W0 : W1;
        const float* Xsrc = (k0 < 256) ? Xc : Qt;
        int koff = k0 & 255;
        #pragma unroll
        for (int i = 0; i < 4; ++i){
            int f = tid + (i << 8);
            int row = f >> 4, c = f & 15;
            float4 av = *(const float4*)&Asrc[(m0 + row) * 256 + koff + (c << 2)];
            float4 xv = *(const float4*)&Xsrc[(n0 + row) * 256 + koff + (c << 2)];
            int kb = (c << 3) ^ ((row & 7) << 4);
            short4 ah; ah.x = f2bf(av.x); ah.y = f2bf(av.y); ah.z = f2bf(av.z); ah.w = f2bf(av.w);
            short4 xh; xh.x = f2bf(xv.x); xh.y = f2bf(xv.y); xh.z = f2bf(xv.z); xh.w = f2bf(xv.w);
            *(short4*)((char*)As + row * 128 + kb) = ah;
            *(short4*)((char*)Xs + row * 128 + kb) = xh;
        }
        __syncthreads();
        int swz = (c16 & 7) << 4;
        bf16x8 a0 = *(const bf16x8*)((const char*)As + ((w << 4) + c16) * 128 + (((q << 4)     ) ^ swz));
        bf16x8 a1 = *(const bf16x8*)((const char*)As + ((w << 4) + c16) * 128 + ((64 + (q << 4)) ^ swz));
        #pragma unroll
        for (int nr = 0; nr < 4; ++nr){
            int xrow = (nr << 4) + c16;
            bf16x8 b0 = *(const bf16x8*)((const char*)Xs + xrow * 128 + (((q << 4)     ) ^ swz));
            bf16x8 b1 = *(const bf16x8*)((const char*)Xs + xrow * 128 + ((64 + (q << 4)) ^ swz));
            acc[nr] = __builtin_amdgcn_mfma_f32_16x16x32_bf16(a0, b0, acc[nr], 0, 0, 0);
            acc[nr] = __builtin_amdgcn_mfma_f32_16x16x32_bf16(a1, b1, acc[nr], 0, 0, 0);
        }
        __syncthreads();
    }
    int mrow = m0 + (w << 4) + (q << 2);
    if (g == 0){
        #pragma unroll
        for (int nr = 0; nr < 4; ++nr){
            int ncol = n0 + (nr << 4) + c16;
            #pragma unroll
            for (int r = 0; r < 4; ++r){
                int idx = (mrow + r) * 1024 + ncol;
                Umat[idx] = sigmoidf_(acc[nr][r] + bu[idx]);
            }
        }
    } else if (g == 1){
        #pragma unroll
        for (int nr = 0; nr < 4; ++nr){
            int ncol = n0 + (nr << 4) + c16;
            float4 o;
            float* op = (float*)&o;
            #pragma unroll
            for (int r = 0; r < 4; ++r){
                int idx = (mrow + r) * 1024 + ncol;
                op[r] = sigmoidf_(acc[nr][r] + br[idx]) * Q[idx];
            }
            *(float4*)&RQt[ncol * 256 + mrow] = o;
        }
    } else {
        #pragma unroll
        for (int nr = 0; nr < 4; ++nr){
            int ncol = n0 + (nr << 4) + c16;
            #pragma unroll
            for (int r = 0; r < 4; ++r){
                int idx = (mrow + r) * 1024 + ncol;
                P3[idx] = acc[nr][r] + bh[idx];
            }
        }
    }
}

__global__ __launch_bounds__(256) void gemm2_mfma(
    const float* __restrict__ Uh, const float* __restrict__ RQt,
    const float* __restrict__ P3, const float* __restrict__ Umat,
    const float* __restrict__ Q, float* __restrict__ out)
{
    __shared__ short As[4096];
    __shared__ short Xs[4096];
    int n0 = blockIdx.x * 64, m0 = blockIdx.y * 64;
    int tid = threadIdx.x;
    int l = tid & 63, w = tid >> 6;
    int q = l >> 4, c16 = l & 15;
    f32x4 acc[4];
    #pragma unroll
    for (int i = 0; i < 4; ++i) acc[i] = (f32x4){0.f, 0.f, 0.f, 0.f};
    for (int k0 = 0; k0 < 256; k0 += 64){
        #pragma unroll
        for (int i = 0; i < 4; ++i){
            int f = tid + (i << 8);
            int row = f >> 4, c = f & 15;
            float4 av = *(const float4*)&Uh[(m0 + row) * 256 + k0 + (c << 2)];
            float4 xv = *(const float4*)&RQt[(n0 + row) * 256 + k0 + (c << 2)];
            int kb = (c << 3) ^ ((row & 7) << 4);
            short4 ah; ah.x = f2bf(av.x); ah.y = f2bf(av.y); ah.z = f2bf(av.z); ah.w = f2bf(av.w);
            short4 xh; xh.x = f2bf(xv.x); xh.y = f2bf(xv.y); xh.z = f2bf(xv.z); xh.w = f2bf(xv.w);
            *(short4*)((char*)As + row * 128 + kb) = ah;
            *(short4*)((char*)Xs + row * 128 + kb) = xh;
        }
        __syncthreads();
        int swz = (c16 & 7) << 4;
        bf16x8 a0 = *(const bf16x8*)((const char*)As + ((w << 4) + c16) * 128 + (((q << 4)     ) ^ swz));
        bf16x8 a1 = *(const bf16x8*)((const char*)As + ((w << 4) + c16) * 128 + ((64 + (q << 4)) ^ swz));
        #pragma unroll
        for (int nr = 0; nr < 4; ++nr){
            int xrow = (nr << 4) + c16;
            bf16x8 b0 = *(const bf16x8*)((const char*)Xs + xrow * 128 + (((q << 4)     ) ^ swz));
            bf16x8 b1 = *(const bf16x8*)((const char*)Xs + xrow * 128 + ((64 + (q << 4)) ^ swz));
            acc[nr] = __builtin_amdgcn_mfma_f32_16x16x32_bf16(a0, b0, acc[nr], 0, 0, 0);
            acc[nr] = __builtin_amdgcn_mfma_f32_16x16x32_bf16(a1, b1, acc[nr], 0, 0, 0);
        }
        __syncthreads();
    }
    int mrow = m0 + (w << 4) + (q << 2);
    #pragma unroll
    for (int nr = 0; nr < 4; ++nr){
        int ncol = n0 + (nr << 4) + c16;
        #pragma unroll
        for (int r = 0; r < 4; ++r){
            int idx = (mrow + r) * 1024 + ncol;
            float h = fmaxf(acc[nr][r] + P3[idx], 0.0f);
            float u = Umat[idx];
            float qv = Q[idx];
            out[idx] = (1.0f - u) * qv + u * h;
        }
    }
}

extern "C" void kernel_launch(void* const* d_in, const int* in_sizes, int n_in,
                              void* d_out, int out_size, void* d_ws, size_t ws_size,
                              hipStream_t stream)
{
    const float* prev_Q = (const float*)d_in[0];
    const float* prev_Z = (const float*)d_in[1];
    const float* mask   = (const float*)d_in[2];
    const float* scorer = (const float*)d_in[3];
    const float* W_u = (const float*)d_in[4];
    const float* U_u = (const float*)d_in[5];
    const float* b_u = (const float*)d_in[6];
    const float* W_r = (const float*)d_in[7];
    const float* U_r = (const float*)d_in[8];
    const float* b_r = (const float*)d_in[9];
    const float* W_h = (const float*)d_in[10];
    const float* U_h = (const float*)d_in[11];
    const float* b_h = (const float*)d_in[12];

    char* ws = (char*)d_ws;
    double*             scores_d = (double*)            (ws + 0);
    unsigned*           hist     = (unsigned*)          (ws + 4000256);
    unsigned*           meta_u   = (unsigned*)          (ws + 4016640);
    unsigned long long* ckey     = (unsigned long long*)(ws + 4016704);
    unsigned*           cidx     = (unsigned*)          (ws + 4049472);
    unsigned*           sel_idx  = (unsigned*)          (ws + 4065856);
    float*              sel_t    = (float*)             (ws + 4069952);
    float*              Xc       = (float*)             (ws + 4100096);
    float*              Qt       = (float*)             (ws + 5148672);
    float*              RQt      = (float*)             (ws + 6197248);
    float*              Umat     = (float*)             (ws + 7245824);
    float*              P3       = (float*)             (ws + 8294400);

    hipMemsetAsync(ws + 4000256, 0, 16448, stream);
    hipLaunchKernelGGL(transposeQ_kernel, dim3(16, 4), dim3(256), 0, stream, prev_Q, Qt);
    hipLaunchKernelGGL(score_kernel, dim3(1024), dim3(256), 0, stream,
                       (const float4*)prev_Z, (const float4*)scorer, mask, scores_d, hist);
    hipLaunchKernelGGL(scan_kernel, dim3(1), dim3(256), 0, stream, hist, meta_u);
    hipLaunchKernelGGL(collect_kernel, dim3(1954), dim3(256), 0, stream,
                       scores_d, meta_u, ckey, cidx);
    hipLaunchKernelGGL(sort_emit_kernel, dim3(1), dim3(1024), 0, stream,
                       ckey, cidx, meta_u, sel_idx, sel_t);
    hipLaunchKernelGGL(gather_kernel, dim3(256), dim3(256), 0, stream,
                       (const float4*)prev_Z, sel_idx, sel_t, (float4*)Xc);
    hipLaunchKernelGGL(gemm1_mfma, dim3(16, 4, 3), dim3(256), 0, stream,
                       W_u, U_u, b_u, W_r, U_r, b_r, W_h, b_h, Xc, Qt, prev_Q,
                       Umat, RQt, P3);
    hipLaunchKernelGGL(gemm2_mfma, dim3(16, 4), dim3(256), 0, stream,
                       U_h, RQt, P3, Umat, prev_Q, (float*)d_out);
}